// Round 1
// baseline (1064.388 us; speedup 1.0000x reference)
//
#include <hip/hip_runtime.h>

#define NBINS 15
#define NCLS  100

// ---------------------------------------------------------------------------
// init: zero the 45-float global histogram in d_ws (harness poisons ws 0xAA)
// ---------------------------------------------------------------------------
__global__ void ece_init_kernel(float* __restrict__ gbins) {
    int i = threadIdx.x;
    if (i < 3 * NBINS) gbins[i] = 0.0f;
}

// ---------------------------------------------------------------------------
// main: one thread per row (grid-stride). Single pass over the row:
//   s    = sum(exp(x_j))          (no max-subtract: |x| < ~7, exp safe in fp32)
//   m,ix = max / first-argmax
//   conf = exp(m)/s ;  acc = (ix == label)
//   bin  = #{ i in 1..15 : i/15 < conf }   (== searchsorted-left - 1)
// Accumulate (count, conf, acc) per bin in LDS, flush once per block.
// ---------------------------------------------------------------------------
__global__ __launch_bounds__(256) void ece_main_kernel(
        const float* __restrict__ logits,
        const int*   __restrict__ labels,
        float*       __restrict__ gbins,
        int n_rows)
{
    __shared__ float sb[3 * NBINS];
    for (int i = threadIdx.x; i < 3 * NBINS; i += blockDim.x) sb[i] = 0.0f;
    __syncthreads();

    const int stride = gridDim.x * blockDim.x;
    for (int r = blockIdx.x * blockDim.x + threadIdx.x; r < n_rows; r += stride) {
        const float4* row = reinterpret_cast<const float4*>(logits + (size_t)r * NCLS);

        float m  = -3.402823466e+38f;
        int   ix = 0;
        float s0 = 0.0f, s1 = 0.0f, s2 = 0.0f, s3 = 0.0f;

        #pragma unroll
        for (int i = 0; i < NCLS / 4; ++i) {
            float4 v = row[i];
            s0 += __expf(v.x);
            s1 += __expf(v.y);
            s2 += __expf(v.z);
            s3 += __expf(v.w);
            // first-occurrence argmax: strict > keeps earliest index
            bool g;
            g = v.x > m; ix = g ? 4 * i + 0 : ix; m = g ? v.x : m;
            g = v.y > m; ix = g ? 4 * i + 1 : ix; m = g ? v.y : m;
            g = v.z > m; ix = g ? 4 * i + 2 : ix; m = g ? v.z : m;
            g = v.w > m; ix = g ? 4 * i + 3 : ix; m = g ? v.w : m;
        }

        float s    = (s0 + s1) + (s2 + s3);
        float conf = __expf(m) / s;
        float acc  = (ix == labels[r]) ? 1.0f : 0.0f;

        int bin = 0;
        #pragma unroll
        for (int i = 1; i <= NBINS; ++i)
            bin += (conf > (float)i * (1.0f / 15.0f)) ? 1 : 0;
        bin = min(bin, NBINS - 1);  // safety; conf < 1 in practice

        atomicAdd(&sb[bin],             1.0f);
        atomicAdd(&sb[NBINS + bin],     conf);
        atomicAdd(&sb[2 * NBINS + bin], acc);
    }

    __syncthreads();
    if (threadIdx.x < 3 * NBINS) atomicAdd(&gbins[threadIdx.x], sb[threadIdx.x]);
}

// ---------------------------------------------------------------------------
// finalize: ece = sum over nonempty bins of |conf_sum - acc_sum| / n
// (|cs/cnt - as/cnt| * cnt/n simplifies; cnt>0 => denom=cnt)
// ---------------------------------------------------------------------------
__global__ void ece_final_kernel(const float* __restrict__ gbins,
                                 float* __restrict__ out,
                                 float inv_n)
{
    int lane = threadIdx.x;
    float term = 0.0f;
    if (lane < NBINS) {
        float cnt = gbins[lane];
        if (cnt > 0.0f) {
            float cs = gbins[NBINS + lane];
            float as = gbins[2 * NBINS + lane];
            term = fabsf(cs - as) * inv_n;
        }
    }
    #pragma unroll
    for (int off = 32; off >= 1; off >>= 1)
        term += __shfl_down(term, off);
    if (lane == 0) out[0] = term;
}

extern "C" void kernel_launch(void* const* d_in, const int* in_sizes, int n_in,
                              void* d_out, int out_size, void* d_ws, size_t ws_size,
                              hipStream_t stream) {
    const float* logits = (const float*)d_in[0];
    const int*   labels = (const int*)d_in[1];
    const int    n_rows = in_sizes[1];

    float* gbins = (float*)d_ws;   // 45 floats
    float* out   = (float*)d_out;

    ece_init_kernel<<<1, 64, 0, stream>>>(gbins);

    // 1024 blocks x 256 threads = 262144 threads, 8 rows/thread.
    // 4 blocks/CU -> 16 waves/CU, enough to hide HBM latency; few enough
    // blocks that the 45-address global-atomic flush tail is negligible.
    ece_main_kernel<<<1024, 256, 0, stream>>>(logits, labels, gbins, n_rows);

    ece_final_kernel<<<1, 64, 0, stream>>>(gbins, out, 1.0f / (float)n_rows);
}